// Round 14
// baseline (169.084 us; speedup 1.0000x reference)
//
#include <hip/hip_runtime.h>
#include <stdint.h>

typedef float f32x4 __attribute__((ext_vector_type(4)));
typedef __bf16 bf16x8 __attribute__((ext_vector_type(8)));
typedef uint32_t u32a  __attribute__((may_alias));
typedef uint2    u2a   __attribute__((may_alias));
typedef uint4    u4a   __attribute__((may_alias));

#define VS 2064   // Vt row stride in elements (2048 + 16: breaks 4KB L2 aliasing)

__device__ __forceinline__ ushort f2b(float f) {
  uint32_t u = __builtin_bit_cast(uint32_t, f);
  u += 0x7FFFu + ((u >> 16) & 1u);   // round-to-nearest-even
  return (ushort)(u >> 16);
}
__device__ __forceinline__ uint32_t b16(uint32_t u) {  // fp32 bits -> bf16 bits (RNE)
  u += 0x7FFFu + ((u >> 16) & 1u);
  return u >> 16;
}
__device__ __forceinline__ float blo(uint32_t a) {   // low bf16 -> f32
  return __builtin_bit_cast(float, a << 16);
}
__device__ __forceinline__ float bhi(uint32_t a) {   // high bf16 -> f32
  return __builtin_bit_cast(float, a & 0xFFFF0000u);
}

__device__ __forceinline__ bf16x8 ld_frag(const ushort* p) {
  u4a u = *(const u4a*)p;            // ds_read_b128 / global_load_dwordx4
  return __builtin_bit_cast(bf16x8, u);
}

// 8 fp32 -> 8 bf16 packed (two dwordx4 loads + RNE pack)
__device__ __forceinline__ u4a cvt8(const float* p) {
  u4a a = *(const u4a*)p, b = *(const u4a*)(p + 4), o;
  o.x = b16(a.x) | (b16(a.y) << 16);
  o.y = b16(a.z) | (b16(a.w) << 16);
  o.z = b16(b.x) | (b16(b.y) << 16);
  o.w = b16(b.z) | (b16(b.w) << 16);
  return o;
}

__device__ __forceinline__ void load_lds16(const void* g, void* l) {
  __builtin_amdgcn_global_load_lds(
      (const __attribute__((address_space(1))) uint32_t*)g,
      (__attribute__((address_space(3))) uint32_t*)l, 16, 0, 0);
}

// ---------------------------------------------------------------------------
// fp32 -> bf16 one-shot convert: x (3145728) then wq/wk/wv/wo (589824 each).
// ---------------------------------------------------------------------------
__global__ __launch_bounds__(256) void convert_kernel(
    const float* __restrict__ x,  const float* __restrict__ wq,
    const float* __restrict__ wk, const float* __restrict__ wv,
    const float* __restrict__ wo,
    ushort* __restrict__ xb,  ushort* __restrict__ wqb,
    ushort* __restrict__ wkb, ushort* __restrict__ wvb,
    ushort* __restrict__ wob)
{
  const size_t NX = 3145728, NW = 589824;
  size_t idx = ((size_t)blockIdx.x * 256 + threadIdx.x) * 8;
  const float* src; ushort* dst; size_t off;
  if      (idx < NX)          { src = x;  dst = xb;  off = idx; }
  else if (idx < NX + NW)     { src = wq; dst = wqb; off = idx - NX; }
  else if (idx < NX + 2 * NW) { src = wk; dst = wkb; off = idx - NX - NW; }
  else if (idx < NX + 3 * NW) { src = wv; dst = wvb; off = idx - NX - 2 * NW; }
  else                        { src = wo; dst = wob; off = idx - NX - 3 * NW; }
  *(u4a*)(dst + off) = cvt8(src + off);
}

// ---------------------------------------------------------------------------
// QKV: C[M,N]=A[M,K]*B[N,K]^T, bf16, fp32 acc. BM=128 BN=128 BK=64, 256 thr
// (r14: BN 64->128, acc 4x4, 32 MFMA/K-step -- the measured 64^2 -> 128^2
// ladder step; 576 blocks, LDS 32KB, VGPR ~160 -> 3 blk/CU, all resident).
// grid (32, 6, 3): z: 0->Q (PRE-SCALED by log2(e)/8), 1->K row-major;
// 2->V written transposed to Vt[b][h][dv][s] (stride VS).
// ---------------------------------------------------------------------------
__global__ __launch_bounds__(256) void gemm_qkv(
    const ushort* __restrict__ A,
    const ushort* __restrict__ B0, const ushort* __restrict__ B1,
    const ushort* __restrict__ B2,
    ushort* __restrict__ Qo, ushort* __restrict__ Ko, ushort* __restrict__ Vt,
    int M, int N, int K)
{
  const ushort* B = blockIdx.z == 0 ? B0 : (blockIdx.z == 1 ? B1 : B2);
  const int m0 = blockIdx.x * 128, n0 = blockIdx.y * 128;
  __shared__ ushort As[128 * 64];   // 16KB, linear chunk order (8 chunks/row)
  __shared__ ushort Bs[128 * 64];   // 16KB
  const int tid = threadIdx.x, wave = tid >> 6, lane = tid & 63;
  const int quad = lane >> 4, l16 = lane & 15;
  const int mw = (wave & 1) * 64, nw = (wave >> 1) * 64;
  f32x4 acc[4][4] = {};

  for (int k0 = 0; k0 < K; k0 += 64) {
    // A: 1024 chunks of 16B (4/thread); chunk c -> row c>>3, col (c&7)*8
#pragma unroll
    for (int i = 0; i < 4; ++i) {
      int c = i * 256 + tid;
      load_lds16(A + (size_t)(m0 + (c >> 3)) * K + k0 + (c & 7) * 8,
                 As + (size_t)(i * 256 + wave * 64) * 8);
    }
    // B: 1024 chunks (4/thread)
#pragma unroll
    for (int i = 0; i < 4; ++i) {
      int c = i * 256 + tid;
      load_lds16(B + (size_t)(n0 + (c >> 3)) * K + k0 + (c & 7) * 8,
                 Bs + (size_t)(i * 256 + wave * 64) * 8);
    }
    __syncthreads();
#pragma unroll
    for (int ks = 0; ks < 2; ++ks) {
      bf16x8 af[4], bfr[4];
#pragma unroll
      for (int i = 0; i < 4; ++i)
        af[i]  = ld_frag(As + (mw + i * 16 + l16) * 64 + ks * 32 + quad * 8);
#pragma unroll
      for (int jj = 0; jj < 4; ++jj)
        bfr[jj] = ld_frag(Bs + (nw + jj * 16 + l16) * 64 + ks * 32 + quad * 8);
#pragma unroll
      for (int i = 0; i < 4; ++i)
#pragma unroll
        for (int jj = 0; jj < 4; ++jj)
          acc[i][jj] = __builtin_amdgcn_mfma_f32_16x16x32_bf16(af[i], bfr[jj], acc[i][jj], 0, 0, 0);
    }
    __syncthreads();
  }
  // C/D layout: col=lane&15 (N), row=quad*4+reg (M)
  if (blockIdx.z < 2) {
    ushort* C = blockIdx.z == 0 ? Qo : Ko;
    // fold 1/sqrt(dk) AND log2(e) into Q so attention uses exp2 directly
    const float sc = blockIdx.z == 0 ? 0.18033688f : 1.0f;
#pragma unroll
    for (int i = 0; i < 4; ++i)
#pragma unroll
      for (int jj = 0; jj < 4; ++jj)
#pragma unroll
        for (int r = 0; r < 4; ++r) {
          int row = m0 + mw + i * 16 + quad * 4 + r;
          int col = n0 + nw + jj * 16 + l16;
          C[(size_t)row * N + col] = f2b(acc[i][jj][r] * sc);
        }
  } else {
    // Vt[b][h][dv][s] (stride VS): h = col>>6, dv = col&63
#pragma unroll
    for (int i = 0; i < 4; ++i)
#pragma unroll
      for (int jj = 0; jj < 4; ++jj) {
        int col = n0 + nw + jj * 16 + l16;
        int h = col >> 6, dv = col & 63;
        int t = m0 + mw + i * 16 + quad * 4;
        int b = t >> 11, s = t & 2047;
        u2a pw;
        pw.x = (uint32_t)f2b(acc[i][jj][0]) | ((uint32_t)f2b(acc[i][jj][1]) << 16);
        pw.y = (uint32_t)f2b(acc[i][jj][2]) | ((uint32_t)f2b(acc[i][jj][3]) << 16);
        *(u2a*)(Vt + (((size_t)b * 12 + h) * 64 + dv) * VS + s) = pw;
      }
  }
}

// ---------------------------------------------------------------------------
// Output projection: C[M,N](fp32) = A[M,K](bf16)*B[N,K]^T(bf16).
// r14: BM=128 BN=64 BK=64 (the proven qkv structure; was 64^2).
// grid (32,12) = 384 blocks, LDS 24KB, 4/CU capacity -> all resident.
// ---------------------------------------------------------------------------
__global__ __launch_bounds__(256) void gemm_out(
    const ushort* __restrict__ A, const ushort* __restrict__ B,
    float* __restrict__ C, int M, int N, int K)
{
  const int m0 = blockIdx.x * 128, n0 = blockIdx.y * 64;
  __shared__ ushort As[128 * 64];
  __shared__ ushort Bs[64 * 64];
  const int tid = threadIdx.x, wave = tid >> 6, lane = tid & 63;
  const int quad = lane >> 4, l16 = lane & 15;
  const int mw = (wave & 1) * 64, nw = (wave >> 1) * 32;
  f32x4 acc[4][2] = {};

  for (int k0 = 0; k0 < K; k0 += 64) {
#pragma unroll
    for (int i = 0; i < 4; ++i) {
      int c = i * 256 + tid;
      load_lds16(A + (size_t)(m0 + (c >> 3)) * K + k0 + (c & 7) * 8,
                 As + (size_t)(i * 256 + wave * 64) * 8);
    }
#pragma unroll
    for (int i = 0; i < 2; ++i) {
      int c = i * 256 + tid;
      load_lds16(B + (size_t)(n0 + (c >> 3)) * K + k0 + (c & 7) * 8,
                 Bs + (size_t)(i * 256 + wave * 64) * 8);
    }
    __syncthreads();
#pragma unroll
    for (int ks = 0; ks < 2; ++ks) {
      bf16x8 af[4], bfr[2];
#pragma unroll
      for (int i = 0; i < 4; ++i)
        af[i]  = ld_frag(As + (mw + i * 16 + l16) * 64 + ks * 32 + quad * 8);
#pragma unroll
      for (int jj = 0; jj < 2; ++jj)
        bfr[jj] = ld_frag(Bs + (nw + jj * 16 + l16) * 64 + ks * 32 + quad * 8);
#pragma unroll
      for (int i = 0; i < 4; ++i)
#pragma unroll
        for (int jj = 0; jj < 2; ++jj)
          acc[i][jj] = __builtin_amdgcn_mfma_f32_16x16x32_bf16(af[i], bfr[jj], acc[i][jj], 0, 0, 0);
    }
    __syncthreads();
  }
#pragma unroll
  for (int i = 0; i < 4; ++i)
#pragma unroll
    for (int jj = 0; jj < 2; ++jj)
#pragma unroll
      for (int r = 0; r < 4; ++r) {
        int row = m0 + mw + i * 16 + quad * 4 + r;
        int col = n0 + nw + jj * 16 + l16;
        C[(size_t)row * N + col] = acc[i][jj][r];
      }
}

// ---------------------------------------------------------------------------
// Causal flash attention == ROUND-12 BEST (total 156.2): 4-way K-split,
// KVBLK=64, pad-72 LDS, XCD-aware swizzle (r13's KVBLK=128 was neutral-to-
// negative -> reverted). Flat grid 1536; nf=(fid&7)*192+(fid>>3) gives each
// XCD 3 contiguous (bb,h) groups -> K/V L2-resident per XCD.
// FIXED-BASE softmax (r6): P = 2^s directly (m=0); l row-sum via MFMA-ones
// (r7); P-pack via v_perm (r7); P-in-reg PV with permuted contraction index
//   kk = g*32 + (e>>2)*16 + quad*4 + (e&3);
// V staged into Vs in the same permuted order (read stays ds_read_b128).
// VGPR ~96 (<=128 mandatory). Emits unnormalized partials + l per strip.
// ---------------------------------------------------------------------------
__global__ __launch_bounds__(256) void attn_kernel(
    const ushort* __restrict__ Qb, const ushort* __restrict__ Kb,
    const ushort* __restrict__ Vt, ushort* __restrict__ Opart,
    float* __restrict__ Lp)
{
  const int S = 2048, DM = 768;
  const int fid = blockIdx.x;
  const int nf  = (fid & 7) * 192 + (fid >> 3);
  const int grp = nf >> 6;            // 0..23  == bb*12 + h
  const int wit = nf & 63;            // pair*4 + j
  const int bb = grp / 12, h = grp % 12;
  const int pair = wit >> 2, j = wit & 3;

  const ushort* Qp  = Qb + (size_t)bb * S * DM + h * 64;
  const ushort* Kp  = Kb + (size_t)bb * S * DM + h * 64;
  const ushort* Vth = Vt + ((size_t)bb * 12 + h) * 64 * VS;   // [dv][s]

  __shared__ ushort Ks[64 * 72];     // [kk][dk], pad 64->72 (9.2 KB)
  __shared__ ushort Vs[64 * 72];     // [dv][kk-permuted], pad 64->72 (9.2 KB)

  const int tid = threadIdx.x, wave = tid >> 6, lane = tid & 63;
  const int quad = lane >> 4, l16 = lane & 15;
  const float NEG_BIG = -1.0e30f;

  const int qtA = pair, qtB = 31 - pair;       // 64-row q-tiles
  const int qgA = qtA * 64 + wave * 16 + l16;
  const int qgB = qtB * 64 + wave * 16 + l16;

  // Q fragments for both strips (B operand of S^T = K*Q^T)
  bf16x8 bqA0 = ld_frag(Qp + (size_t)qgA * DM + quad * 8);
  bf16x8 bqA1 = ld_frag(Qp + (size_t)qgA * DM + 32 + quad * 8);
  bf16x8 bqB0 = ld_frag(Qp + (size_t)qgB * DM + quad * 8);
  bf16x8 bqB1 = ld_frag(Qp + (size_t)qgB * DM + 32 + quad * 8);

  // ones B-operand for the l row-sum MFMA (bf16 1.0 = 0x3F80)
  u4a one4; one4.x = one4.y = one4.z = one4.w = 0x3F803F80u;
  const bf16x8 ones = __builtin_bit_cast(bf16x8, one4);

  f32x4 accA[4] = {}, accB[4] = {};
  f32x4 alA = {}, alB = {};          // l accumulators (q = wave*16+quad*4+r)

  for (int kt = j; kt <= qtB; kt += 4) {
    const int kk0 = kt * 64;
    // stage K tile: 512 chunks of 16B (2/thread); chunk c -> row c>>3, col (c&7)*8
#pragma unroll
    for (int i = 0; i < 2; ++i) {
      int c = i * 256 + tid;
      int r = c >> 3, col = (c & 7) * 8;
      *(u4a*)(Ks + r * 72 + col) = *(const u4a*)(Kp + (size_t)(kk0 + r) * DM + col);
    }
    // stage V tile from Vt with kk-permuted placement:
    // chunk c -> dv c>>3, global kk run (c&7)*8..+7 lands at
    // pos = (kc8>>2)*32 + (kc8&1)*16 + ((kc8>>1)&1)*4  (first 4) and pos+8.
#pragma unroll
    for (int i = 0; i < 2; ++i) {
      int c = i * 256 + tid;
      int dv = c >> 3, kc8 = c & 7;
      u4a g = *(const u4a*)(Vth + (size_t)dv * VS + kk0 + kc8 * 8);
      int pos = ((kc8 >> 2) * 32) + ((kc8 & 1) * 16) + (((kc8 >> 1) & 1) * 4);
      u2a lo, hi;
      lo.x = g.x; lo.y = g.y; hi.x = g.z; hi.y = g.w;
      *(u2a*)(Vs + dv * 72 + pos)     = lo;
      *(u2a*)(Vs + dv * 72 + pos + 8) = hi;
    }
    __syncthreads();

    // ---- compute one strip from the staged tile (fixed-base softmax) ----
    auto strip = [&](const bf16x8& bq0, const bf16x8& bq1, f32x4* acc_o,
                     f32x4& acc_l, int qg, bool domask) {
      // S^T strip: this wave's 16 q cols x 64 kk rows = 4 tiles
      f32x4 sacc[4] = {};
#pragma unroll
      for (int tt = 0; tt < 4; ++tt) {
        bf16x8 ak0 = ld_frag(Ks + (tt * 16 + l16) * 72 + quad * 8);
        bf16x8 ak1 = ld_frag(Ks + (tt * 16 + l16) * 72 + 32 + quad * 8);
        sacc[tt] = __builtin_amdgcn_mfma_f32_16x16x32_bf16(ak0, bq0, sacc[tt], 0, 0, 0);
        sacc[tt] = __builtin_amdgcn_mfma_f32_16x16x32_bf16(ak1, bq1, sacc[tt], 0, 0, 0);
      }
      // causal mask (diagonal tile only; block-uniform predicate)
      if (domask) {
#pragma unroll
        for (int tt = 0; tt < 4; ++tt)
#pragma unroll
          for (int r = 0; r < 4; ++r) {
            int kkg = kk0 + tt * 16 + quad * 4 + r;
            if (kkg > qg) sacc[tt][r] = NEG_BIG;
          }
      }
      // fused P = 2^s + perm-pack + PV per 32-wide k-group; l via MFMA-ones.
#pragma unroll
      for (int g = 0; g < 2; ++g) {
        u4a pu;
        {
          int tt = g * 2;
          uint32_t u0 = __builtin_bit_cast(uint32_t, exp2f(sacc[tt][0]));
          uint32_t u1 = __builtin_bit_cast(uint32_t, exp2f(sacc[tt][1]));
          uint32_t u2 = __builtin_bit_cast(uint32_t, exp2f(sacc[tt][2]));
          uint32_t u3 = __builtin_bit_cast(uint32_t, exp2f(sacc[tt][3]));
          pu.x = __builtin_amdgcn_perm(u1, u0, 0x07060302u);  // {u1.hi,u0.hi}
          pu.y = __builtin_amdgcn_perm(u3, u2, 0x07060302u);
          u0 = __builtin_bit_cast(uint32_t, exp2f(sacc[tt + 1][0]));
          u1 = __builtin_bit_cast(uint32_t, exp2f(sacc[tt + 1][1]));
          u2 = __builtin_bit_cast(uint32_t, exp2f(sacc[tt + 1][2]));
          u3 = __builtin_bit_cast(uint32_t, exp2f(sacc[tt + 1][3]));
          pu.z = __builtin_amdgcn_perm(u1, u0, 0x07060302u);
          pu.w = __builtin_amdgcn_perm(u3, u2, 0x07060302u);
        }
        bf16x8 ap = __builtin_bit_cast(bf16x8, pu);
        acc_l = __builtin_amdgcn_mfma_f32_16x16x32_bf16(ap, ones, acc_l, 0, 0, 0);
#pragma unroll
        for (int ct = 0; ct < 4; ++ct) {
          bf16x8 bv = ld_frag(Vs + (size_t)(ct * 16 + l16) * 72 + g * 32 + quad * 8);
          acc_o[ct] = __builtin_amdgcn_mfma_f32_16x16x32_bf16(ap, bv, acc_o[ct], 0, 0, 0);
        }
      }
    };

    strip(bqB0, bqB1, accB, alB, qgB, kt == qtB);     // always active
    if (kt <= qtA)
      strip(bqA0, bqA1, accA, alA, qgA, kt == qtA);   // block-uniform branch
    __syncthreads();   // protect Ks/Vs before next restage
  }

  // epilogue: store partials; l for q=wave*16+quad*4+r is acc_l[r],
  // identical across l16 lanes -> store from l16==0.
  const int base = ((bb * 12 + h) << 5);
  const int r0 = wave * 16 + quad * 4;
  {
    const int slot = (base + qtB) * 4 + j;
    ushort* Os = Opart + (size_t)slot * 4096;
#pragma unroll
    for (int ct = 0; ct < 4; ++ct) {
      int col = ct * 16 + l16;
      Os[(r0 + 0) * 64 + col] = f2b(accB[ct][0]);
      Os[(r0 + 1) * 64 + col] = f2b(accB[ct][1]);
      Os[(r0 + 2) * 64 + col] = f2b(accB[ct][2]);
      Os[(r0 + 3) * 64 + col] = f2b(accB[ct][3]);
    }
    if (l16 == 0) {
#pragma unroll
      for (int r = 0; r < 4; ++r)
        Lp[(size_t)slot * 64 + r0 + r] = alB[r];
    }
  }
  {
    const int slot = (base + qtA) * 4 + j;
    ushort* Os = Opart + (size_t)slot * 4096;
#pragma unroll
    for (int ct = 0; ct < 4; ++ct) {
      int col = ct * 16 + l16;
      Os[(r0 + 0) * 64 + col] = f2b(accA[ct][0]);
      Os[(r0 + 1) * 64 + col] = f2b(accA[ct][1]);
      Os[(r0 + 2) * 64 + col] = f2b(accA[ct][2]);
      Os[(r0 + 3) * 64 + col] = f2b(accA[ct][3]);
    }
    if (l16 == 0) {
#pragma unroll
      for (int r = 0; r < 4; ++r)
        Lp[(size_t)slot * 64 + r0 + r] = alA[r];
    }
  }
}

// ---------------------------------------------------------------------------
// Combine the four K-parity partials per strip -> Abuf (b, s, h*64) bf16.
// grid 768 (one block per strip), 256 threads, 16 elems/thread.
// All partials share base m=0 -> weights are uniformly 1/sum(l): accumulate
// raw O sums, scale once. Empty partials have l=0, O=0 (every strip's j=0
// block always runs kt=0, so denom > 0; ALL slots are written).
// ---------------------------------------------------------------------------
__global__ __launch_bounds__(256) void combine_kernel(
    const ushort* __restrict__ Opart, const float* __restrict__ Lp,
    ushort* __restrict__ Ab, int split)
{
  const int sid = blockIdx.x;
  const int bb = sid / 384, rem = sid % 384, h = rem >> 5, qt = rem & 31;
  const int t = threadIdx.x, row = t >> 2, cg = (t & 3) * 16;
  const float* lp = Lp + (size_t)sid * split * 64 + row;
  float denom = 0.0f;
  for (int i = 0; i < split; ++i) denom += lp[(size_t)i * 64];
  const float inv = 1.0f / denom;
  float os[16] = {};
  const ushort* p0 = Opart + (size_t)sid * split * 4096 + row * 64 + cg;
  for (int i = 0; i < split; ++i) {
#pragma unroll
    for (int g = 0; g < 2; ++g) {
      u4a a = *(const u4a*)(p0 + (size_t)i * 4096 + g * 8);
      os[g * 8 + 0] += blo(a.x); os[g * 8 + 1] += bhi(a.x);
      os[g * 8 + 2] += blo(a.y); os[g * 8 + 3] += bhi(a.y);
      os[g * 8 + 4] += blo(a.z); os[g * 8 + 5] += bhi(a.z);
      os[g * 8 + 6] += blo(a.w); os[g * 8 + 7] += bhi(a.w);
    }
  }
  ushort* dst = Ab + ((size_t)(bb * 2048 + qt * 64 + row)) * 768 + h * 64 + cg;
#pragma unroll
  for (int g = 0; g < 2; ++g) {
    u4a o;
    o.x = (uint32_t)f2b(os[g * 8 + 0] * inv) | ((uint32_t)f2b(os[g * 8 + 1] * inv) << 16);
    o.y = (uint32_t)f2b(os[g * 8 + 2] * inv) | ((uint32_t)f2b(os[g * 8 + 3] * inv) << 16);
    o.z = (uint32_t)f2b(os[g * 8 + 4] * inv) | ((uint32_t)f2b(os[g * 8 + 5] * inv) << 16);
    o.w = (uint32_t)f2b(os[g * 8 + 6] * inv) | ((uint32_t)f2b(os[g * 8 + 7] * inv) << 16);
    *(u4a*)(dst + g * 8) = o;
  }
}

// ---------------------------------------------------------------------------
extern "C" void kernel_launch(void* const* d_in, const int* in_sizes, int n_in,
                              void* d_out, int out_size, void* d_ws, size_t ws_size,
                              hipStream_t stream) {
  (void)in_sizes; (void)n_in; (void)out_size; (void)ws_size;
  const float* x  = (const float*)d_in[0];
  const float* wq = (const float*)d_in[1];
  const float* wk = (const float*)d_in[2];
  const float* wv = (const float*)d_in[3];
  const float* wo = (const float*)d_in[4];

  const size_t NT = (size_t)4096 * 768;   // tokens x d_model
  const size_t NW = (size_t)768 * 768;
  const size_t NV = (size_t)24 * 64 * VS; // padded Vt
  ushort* xb    = (ushort*)d_ws;          // reused as Abuf after QKV GEMM
  ushort* Qbuf  = xb + NT;
  ushort* Kbuf  = Qbuf + NT;
  ushort* Vt    = Kbuf + NT;              // (b, h, dv, s) stride VS
  ushort* wqb   = Vt + NV;
  ushort* wkb   = wqb + NW;
  ushort* wvb   = wkb + NW;
  ushort* wob   = wvb + NW;
  ushort* Opart = wob + NW;               // 3072 x 64 x 64 bf16
  float* Lp     = (float*)(Opart + (size_t)3072 * 4096);  // 3072 x 64
  ushort* Abuf  = xb;                     // lifetime-disjoint reuse

  // fp32 -> bf16 (x + all weights)
  convert_kernel<<<2688, 256, 0, stream>>>(x, wq, wk, wv, wo,
                                           xb, wqb, wkb, wvb, wob);
  // Q/K/V projections: 128x128 tile (r14), Q pre-scaled, V -> Vt transposed
  gemm_qkv<<<dim3(32, 6, 3), 256, 0, stream>>>(
      xb, wqb, wkb, wvb, Qbuf, Kbuf, Vt, 4096, 768, 768);
  // causal flash attention: r12 best (XCD swizzle, 4-way split, KVBLK=64)
  attn_kernel<<<1536, 256, 0, stream>>>(Qbuf, Kbuf, Vt, Opart, Lp);
  // merge partials -> Abuf
  combine_kernel<<<768, 256, 0, stream>>>(Opart, Lp, Abuf, 4);
  // output projection: 128x64 tile (r14), fp32 out
  gemm_out<<<dim3(32, 12), 256, 0, stream>>>(
      Abuf, wob, (float*)d_out, 4096, 768, 768);
}

// Round 15
// 160.584 us; speedup vs baseline: 1.0529x; 1.0529x over previous
//
#include <hip/hip_runtime.h>
#include <stdint.h>

typedef float f32x4 __attribute__((ext_vector_type(4)));
typedef __bf16 bf16x8 __attribute__((ext_vector_type(8)));
typedef uint32_t u32a  __attribute__((may_alias));
typedef uint2    u2a   __attribute__((may_alias));
typedef uint4    u4a   __attribute__((may_alias));

#define VS 2064   // Vt row stride in elements (2048 + 16: breaks 4KB L2 aliasing)

__device__ __forceinline__ ushort f2b(float f) {
  uint32_t u = __builtin_bit_cast(uint32_t, f);
  u += 0x7FFFu + ((u >> 16) & 1u);   // round-to-nearest-even
  return (ushort)(u >> 16);
}
__device__ __forceinline__ uint32_t b16(uint32_t u) {  // fp32 bits -> bf16 bits (RNE)
  u += 0x7FFFu + ((u >> 16) & 1u);
  return u >> 16;
}
__device__ __forceinline__ float blo(uint32_t a) {   // low bf16 -> f32
  return __builtin_bit_cast(float, a << 16);
}
__device__ __forceinline__ float bhi(uint32_t a) {   // high bf16 -> f32
  return __builtin_bit_cast(float, a & 0xFFFF0000u);
}

__device__ __forceinline__ bf16x8 ld_frag(const ushort* p) {
  u4a u = *(const u4a*)p;            // ds_read_b128 / global_load_dwordx4
  return __builtin_bit_cast(bf16x8, u);
}

// 8 fp32 -> 8 bf16 packed (two dwordx4 loads + RNE pack)
__device__ __forceinline__ u4a cvt8(const float* p) {
  u4a a = *(const u4a*)p, b = *(const u4a*)(p + 4), o;
  o.x = b16(a.x) | (b16(a.y) << 16);
  o.y = b16(a.z) | (b16(a.w) << 16);
  o.z = b16(b.x) | (b16(b.y) << 16);
  o.w = b16(b.z) | (b16(b.w) << 16);
  return o;
}

__device__ __forceinline__ void load_lds16(const void* g, void* l) {
  __builtin_amdgcn_global_load_lds(
      (const __attribute__((address_space(1))) uint32_t*)g,
      (__attribute__((address_space(3))) uint32_t*)l, 16, 0, 0);
}

// ---------------------------------------------------------------------------
// fp32 -> bf16 one-shot convert: x (3145728) then wq/wk/wv/wo (589824 each).
// ---------------------------------------------------------------------------
__global__ __launch_bounds__(256) void convert_kernel(
    const float* __restrict__ x,  const float* __restrict__ wq,
    const float* __restrict__ wk, const float* __restrict__ wv,
    const float* __restrict__ wo,
    ushort* __restrict__ xb,  ushort* __restrict__ wqb,
    ushort* __restrict__ wkb, ushort* __restrict__ wvb,
    ushort* __restrict__ wob)
{
  const size_t NX = 3145728, NW = 589824;
  size_t idx = ((size_t)blockIdx.x * 256 + threadIdx.x) * 8;
  const float* src; ushort* dst; size_t off;
  if      (idx < NX)          { src = x;  dst = xb;  off = idx; }
  else if (idx < NX + NW)     { src = wq; dst = wqb; off = idx - NX; }
  else if (idx < NX + 2 * NW) { src = wk; dst = wkb; off = idx - NX - NW; }
  else if (idx < NX + 3 * NW) { src = wv; dst = wvb; off = idx - NX - 2 * NW; }
  else                        { src = wo; dst = wob; off = idx - NX - 3 * NW; }
  *(u4a*)(dst + off) = cvt8(src + off);
}

// ---------------------------------------------------------------------------
// QKV: C[M,N]=A[M,K]*B[N,K]^T, bf16, fp32 acc. BM=128 BN=64 BK=64, 256 thr
// (r12-proven tile; r14's 128x128 shrank the grid below one residency round
// on this SKINNY N=768 problem -> -13us; reverted). Flat grid 1152 with
// XCD swizzle: nf=(fid&7)*144+(fid>>3) (bijective, 1152=8*144) so each XCD
// gets contiguous logical blocks -> B weight panels L2-resident per XCD.
// Decode: z = nf/384 (0->Q pre-scaled by log2e/8, 1->K, 2->V->Vt transposed),
// y = (nf%384)>>5 tiles N, x = nf&31 tiles M.
// ---------------------------------------------------------------------------
__global__ __launch_bounds__(256) void gemm_qkv(
    const ushort* __restrict__ A,
    const ushort* __restrict__ B0, const ushort* __restrict__ B1,
    const ushort* __restrict__ B2,
    ushort* __restrict__ Qo, ushort* __restrict__ Ko, ushort* __restrict__ Vt,
    int M, int N, int K)
{
  const int fid = blockIdx.x;
  const int nf  = (fid & 7) * 144 + (fid >> 3);
  const int bz = nf / 384, rem = nf % 384, by = rem >> 5, bx = rem & 31;
  const ushort* B = bz == 0 ? B0 : (bz == 1 ? B1 : B2);
  const int m0 = bx * 128, n0 = by * 64;
  __shared__ ushort As[128 * 64];   // 16KB, linear chunk order (8 chunks/row)
  __shared__ ushort Bs[64 * 64];    // 8KB
  const int tid = threadIdx.x, wave = tid >> 6, lane = tid & 63;
  const int quad = lane >> 4, l16 = lane & 15;
  const int mw = (wave & 1) * 64, nw = (wave >> 1) * 32;
  f32x4 acc[4][2] = {};

  for (int k0 = 0; k0 < K; k0 += 64) {
    // A: 1024 chunks of 16B (4/thread); chunk c -> row c>>3, col (c&7)*8
#pragma unroll
    for (int i = 0; i < 4; ++i) {
      int c = i * 256 + tid;
      load_lds16(A + (size_t)(m0 + (c >> 3)) * K + k0 + (c & 7) * 8,
                 As + (size_t)(i * 256 + wave * 64) * 8);
    }
    // B: 512 chunks (2/thread)
#pragma unroll
    for (int i = 0; i < 2; ++i) {
      int c = i * 256 + tid;
      load_lds16(B + (size_t)(n0 + (c >> 3)) * K + k0 + (c & 7) * 8,
                 Bs + (size_t)(i * 256 + wave * 64) * 8);
    }
    __syncthreads();
#pragma unroll
    for (int ks = 0; ks < 2; ++ks) {
      bf16x8 af[4], bfr[2];
#pragma unroll
      for (int i = 0; i < 4; ++i)
        af[i]  = ld_frag(As + (mw + i * 16 + l16) * 64 + ks * 32 + quad * 8);
#pragma unroll
      for (int jj = 0; jj < 2; ++jj)
        bfr[jj] = ld_frag(Bs + (nw + jj * 16 + l16) * 64 + ks * 32 + quad * 8);
#pragma unroll
      for (int i = 0; i < 4; ++i)
#pragma unroll
        for (int jj = 0; jj < 2; ++jj)
          acc[i][jj] = __builtin_amdgcn_mfma_f32_16x16x32_bf16(af[i], bfr[jj], acc[i][jj], 0, 0, 0);
    }
    __syncthreads();
  }
  // C/D layout: col=lane&15 (N), row=quad*4+reg (M)
  if (bz < 2) {
    ushort* C = bz == 0 ? Qo : Ko;
    // fold 1/sqrt(dk) AND log2(e) into Q so attention uses exp2 directly
    const float sc = bz == 0 ? 0.18033688f : 1.0f;
#pragma unroll
    for (int i = 0; i < 4; ++i)
#pragma unroll
      for (int jj = 0; jj < 2; ++jj)
#pragma unroll
        for (int r = 0; r < 4; ++r) {
          int row = m0 + mw + i * 16 + quad * 4 + r;
          int col = n0 + nw + jj * 16 + l16;
          C[(size_t)row * N + col] = f2b(acc[i][jj][r] * sc);
        }
  } else {
    // Vt[b][h][dv][s] (stride VS): h = col>>6, dv = col&63
#pragma unroll
    for (int i = 0; i < 4; ++i)
#pragma unroll
      for (int jj = 0; jj < 2; ++jj) {
        int col = n0 + nw + jj * 16 + l16;
        int h = col >> 6, dv = col & 63;
        int t = m0 + mw + i * 16 + quad * 4;
        int b = t >> 11, s = t & 2047;
        u2a pw;
        pw.x = (uint32_t)f2b(acc[i][jj][0]) | ((uint32_t)f2b(acc[i][jj][1]) << 16);
        pw.y = (uint32_t)f2b(acc[i][jj][2]) | ((uint32_t)f2b(acc[i][jj][3]) << 16);
        *(u2a*)(Vt + (((size_t)b * 12 + h) * 64 + dv) * VS + s) = pw;
      }
  }
}

// ---------------------------------------------------------------------------
// Output projection: C[M,N](fp32) = A[M,K](bf16)*B[N,K]^T(bf16).
// BM=BN=64, BK=64, 256 thr (r12-proven; r14's 128x64 halved the grid ->
// reverted). Flat grid 768 with XCD swizzle nf=(fid&7)*96+(fid>>3)
// (bijective, 768=8*96): same-y blocks (shared wob panel) colocate per XCD.
// ---------------------------------------------------------------------------
__global__ __launch_bounds__(256) void gemm_out(
    const ushort* __restrict__ A, const ushort* __restrict__ B,
    float* __restrict__ C, int M, int N, int K)
{
  const int fid = blockIdx.x;
  const int nf  = (fid & 7) * 96 + (fid >> 3);
  const int bx = nf & 63, by = nf >> 6;
  const int m0 = bx * 64, n0 = by * 64;
  __shared__ ushort As[64 * 64];
  __shared__ ushort Bs[64 * 64];
  const int tid = threadIdx.x, wave = tid >> 6, lane = tid & 63;
  const int quad = lane >> 4, l16 = lane & 15;
  const int mw = (wave & 1) * 32, nw = (wave >> 1) * 32;
  f32x4 acc[2][2] = {};

  for (int k0 = 0; k0 < K; k0 += 64) {
#pragma unroll
    for (int i = 0; i < 2; ++i) {
      int c = i * 256 + tid;
      load_lds16(A + (size_t)(m0 + (c >> 3)) * K + k0 + (c & 7) * 8,
                 As + (size_t)(i * 256 + wave * 64) * 8);
      load_lds16(B + (size_t)(n0 + (c >> 3)) * K + k0 + (c & 7) * 8,
                 Bs + (size_t)(i * 256 + wave * 64) * 8);
    }
    __syncthreads();
#pragma unroll
    for (int ks = 0; ks < 2; ++ks) {
      bf16x8 af[2], bfr[2];
#pragma unroll
      for (int i = 0; i < 2; ++i)
        af[i]  = ld_frag(As + (mw + i * 16 + l16) * 64 + ks * 32 + quad * 8);
#pragma unroll
      for (int jj = 0; jj < 2; ++jj)
        bfr[jj] = ld_frag(Bs + (nw + jj * 16 + l16) * 64 + ks * 32 + quad * 8);
#pragma unroll
      for (int i = 0; i < 2; ++i)
#pragma unroll
        for (int jj = 0; jj < 2; ++jj)
          acc[i][jj] = __builtin_amdgcn_mfma_f32_16x16x32_bf16(af[i], bfr[jj], acc[i][jj], 0, 0, 0);
    }
    __syncthreads();
  }
#pragma unroll
  for (int i = 0; i < 2; ++i)
#pragma unroll
    for (int jj = 0; jj < 2; ++jj)
#pragma unroll
      for (int r = 0; r < 4; ++r) {
        int row = m0 + mw + i * 16 + quad * 4 + r;
        int col = n0 + nw + jj * 16 + l16;
        C[(size_t)row * N + col] = acc[i][jj][r];
      }
}

// ---------------------------------------------------------------------------
// Causal flash attention == ROUND-12 BEST (total 156.2): 4-way K-split,
// KVBLK=64, pad-72 LDS, XCD-aware swizzle. Flat grid 1536;
// nf=(fid&7)*192+(fid>>3) gives each XCD 3 contiguous (bb,h) groups ->
// K/V L2-resident per XCD.
// FIXED-BASE softmax (r6): P = 2^s directly (m=0); l row-sum via MFMA-ones
// (r7); P-pack via v_perm (r7); P-in-reg PV with permuted contraction index
//   kk = g*32 + (e>>2)*16 + quad*4 + (e&3);
// V staged into Vs in the same permuted order (read stays ds_read_b128).
// VGPR ~96 (<=128 mandatory). Emits unnormalized partials + l per strip.
// (Refuted levers: dbuf r9, strip-fusion r10, KVBLK=128 r13 -- keep as-is.)
// ---------------------------------------------------------------------------
__global__ __launch_bounds__(256) void attn_kernel(
    const ushort* __restrict__ Qb, const ushort* __restrict__ Kb,
    const ushort* __restrict__ Vt, ushort* __restrict__ Opart,
    float* __restrict__ Lp)
{
  const int S = 2048, DM = 768;
  const int fid = blockIdx.x;
  const int nf  = (fid & 7) * 192 + (fid >> 3);
  const int grp = nf >> 6;            // 0..23  == bb*12 + h
  const int wit = nf & 63;            // pair*4 + j
  const int bb = grp / 12, h = grp % 12;
  const int pair = wit >> 2, j = wit & 3;

  const ushort* Qp  = Qb + (size_t)bb * S * DM + h * 64;
  const ushort* Kp  = Kb + (size_t)bb * S * DM + h * 64;
  const ushort* Vth = Vt + ((size_t)bb * 12 + h) * 64 * VS;   // [dv][s]

  __shared__ ushort Ks[64 * 72];     // [kk][dk], pad 64->72 (9.2 KB)
  __shared__ ushort Vs[64 * 72];     // [dv][kk-permuted], pad 64->72 (9.2 KB)

  const int tid = threadIdx.x, wave = tid >> 6, lane = tid & 63;
  const int quad = lane >> 4, l16 = lane & 15;
  const float NEG_BIG = -1.0e30f;

  const int qtA = pair, qtB = 31 - pair;       // 64-row q-tiles
  const int qgA = qtA * 64 + wave * 16 + l16;
  const int qgB = qtB * 64 + wave * 16 + l16;

  // Q fragments for both strips (B operand of S^T = K*Q^T)
  bf16x8 bqA0 = ld_frag(Qp + (size_t)qgA * DM + quad * 8);
  bf16x8 bqA1 = ld_frag(Qp + (size_t)qgA * DM + 32 + quad * 8);
  bf16x8 bqB0 = ld_frag(Qp + (size_t)qgB * DM + quad * 8);
  bf16x8 bqB1 = ld_frag(Qp + (size_t)qgB * DM + 32 + quad * 8);

  // ones B-operand for the l row-sum MFMA (bf16 1.0 = 0x3F80)
  u4a one4; one4.x = one4.y = one4.z = one4.w = 0x3F803F80u;
  const bf16x8 ones = __builtin_bit_cast(bf16x8, one4);

  f32x4 accA[4] = {}, accB[4] = {};
  f32x4 alA = {}, alB = {};          // l accumulators (q = wave*16+quad*4+r)

  for (int kt = j; kt <= qtB; kt += 4) {
    const int kk0 = kt * 64;
    // stage K tile: 512 chunks of 16B (2/thread); chunk c -> row c>>3, col (c&7)*8
#pragma unroll
    for (int i = 0; i < 2; ++i) {
      int c = i * 256 + tid;
      int r = c >> 3, col = (c & 7) * 8;
      *(u4a*)(Ks + r * 72 + col) = *(const u4a*)(Kp + (size_t)(kk0 + r) * DM + col);
    }
    // stage V tile from Vt with kk-permuted placement:
    // chunk c -> dv c>>3, global kk run (c&7)*8..+7 lands at
    // pos = (kc8>>2)*32 + (kc8&1)*16 + ((kc8>>1)&1)*4  (first 4) and pos+8.
#pragma unroll
    for (int i = 0; i < 2; ++i) {
      int c = i * 256 + tid;
      int dv = c >> 3, kc8 = c & 7;
      u4a g = *(const u4a*)(Vth + (size_t)dv * VS + kk0 + kc8 * 8);
      int pos = ((kc8 >> 2) * 32) + ((kc8 & 1) * 16) + (((kc8 >> 1) & 1) * 4);
      u2a lo, hi;
      lo.x = g.x; lo.y = g.y; hi.x = g.z; hi.y = g.w;
      *(u2a*)(Vs + dv * 72 + pos)     = lo;
      *(u2a*)(Vs + dv * 72 + pos + 8) = hi;
    }
    __syncthreads();

    // ---- compute one strip from the staged tile (fixed-base softmax) ----
    auto strip = [&](const bf16x8& bq0, const bf16x8& bq1, f32x4* acc_o,
                     f32x4& acc_l, int qg, bool domask) {
      // S^T strip: this wave's 16 q cols x 64 kk rows = 4 tiles
      f32x4 sacc[4] = {};
#pragma unroll
      for (int tt = 0; tt < 4; ++tt) {
        bf16x8 ak0 = ld_frag(Ks + (tt * 16 + l16) * 72 + quad * 8);
        bf16x8 ak1 = ld_frag(Ks + (tt * 16 + l16) * 72 + 32 + quad * 8);
        sacc[tt] = __builtin_amdgcn_mfma_f32_16x16x32_bf16(ak0, bq0, sacc[tt], 0, 0, 0);
        sacc[tt] = __builtin_amdgcn_mfma_f32_16x16x32_bf16(ak1, bq1, sacc[tt], 0, 0, 0);
      }
      // causal mask (diagonal tile only; block-uniform predicate)
      if (domask) {
#pragma unroll
        for (int tt = 0; tt < 4; ++tt)
#pragma unroll
          for (int r = 0; r < 4; ++r) {
            int kkg = kk0 + tt * 16 + quad * 4 + r;
            if (kkg > qg) sacc[tt][r] = NEG_BIG;
          }
      }
      // fused P = 2^s + perm-pack + PV per 32-wide k-group; l via MFMA-ones.
#pragma unroll
      for (int g = 0; g < 2; ++g) {
        u4a pu;
        {
          int tt = g * 2;
          uint32_t u0 = __builtin_bit_cast(uint32_t, exp2f(sacc[tt][0]));
          uint32_t u1 = __builtin_bit_cast(uint32_t, exp2f(sacc[tt][1]));
          uint32_t u2 = __builtin_bit_cast(uint32_t, exp2f(sacc[tt][2]));
          uint32_t u3 = __builtin_bit_cast(uint32_t, exp2f(sacc[tt][3]));
          pu.x = __builtin_amdgcn_perm(u1, u0, 0x07060302u);  // {u1.hi,u0.hi}
          pu.y = __builtin_amdgcn_perm(u3, u2, 0x07060302u);
          u0 = __builtin_bit_cast(uint32_t, exp2f(sacc[tt + 1][0]));
          u1 = __builtin_bit_cast(uint32_t, exp2f(sacc[tt + 1][1]));
          u2 = __builtin_bit_cast(uint32_t, exp2f(sacc[tt + 1][2]));
          u3 = __builtin_bit_cast(uint32_t, exp2f(sacc[tt + 1][3]));
          pu.z = __builtin_amdgcn_perm(u1, u0, 0x07060302u);
          pu.w = __builtin_amdgcn_perm(u3, u2, 0x07060302u);
        }
        bf16x8 ap = __builtin_bit_cast(bf16x8, pu);
        acc_l = __builtin_amdgcn_mfma_f32_16x16x32_bf16(ap, ones, acc_l, 0, 0, 0);
#pragma unroll
        for (int ct = 0; ct < 4; ++ct) {
          bf16x8 bv = ld_frag(Vs + (size_t)(ct * 16 + l16) * 72 + g * 32 + quad * 8);
          acc_o[ct] = __builtin_amdgcn_mfma_f32_16x16x32_bf16(ap, bv, acc_o[ct], 0, 0, 0);
        }
      }
    };

    strip(bqB0, bqB1, accB, alB, qgB, kt == qtB);     // always active
    if (kt <= qtA)
      strip(bqA0, bqA1, accA, alA, qgA, kt == qtA);   // block-uniform branch
    __syncthreads();   // protect Ks/Vs before next restage
  }

  // epilogue: store partials; l for q=wave*16+quad*4+r is acc_l[r],
  // identical across l16 lanes -> store from l16==0.
  const int base = ((bb * 12 + h) << 5);
  const int r0 = wave * 16 + quad * 4;
  {
    const int slot = (base + qtB) * 4 + j;
    ushort* Os = Opart + (size_t)slot * 4096;
#pragma unroll
    for (int ct = 0; ct < 4; ++ct) {
      int col = ct * 16 + l16;
      Os[(r0 + 0) * 64 + col] = f2b(accB[ct][0]);
      Os[(r0 + 1) * 64 + col] = f2b(accB[ct][1]);
      Os[(r0 + 2) * 64 + col] = f2b(accB[ct][2]);
      Os[(r0 + 3) * 64 + col] = f2b(accB[ct][3]);
    }
    if (l16 == 0) {
#pragma unroll
      for (int r = 0; r < 4; ++r)
        Lp[(size_t)slot * 64 + r0 + r] = alB[r];
    }
  }
  {
    const int slot = (base + qtA) * 4 + j;
    ushort* Os = Opart + (size_t)slot * 4096;
#pragma unroll
    for (int ct = 0; ct < 4; ++ct) {
      int col = ct * 16 + l16;
      Os[(r0 + 0) * 64 + col] = f2b(accA[ct][0]);
      Os[(r0 + 1) * 64 + col] = f2b(accA[ct][1]);
      Os[(r0 + 2) * 64 + col] = f2b(accA[ct][2]);
      Os[(r0 + 3) * 64 + col] = f2b(accA[ct][3]);
    }
    if (l16 == 0) {
#pragma unroll
      for (int r = 0; r < 4; ++r)
        Lp[(size_t)slot * 64 + r0 + r] = alA[r];
    }
  }
}

// ---------------------------------------------------------------------------
// Combine the four K-parity partials per strip -> Abuf (b, s, h*64) bf16.
// grid 768 (one block per strip), 256 threads, 16 elems/thread.
// All partials share base m=0 -> weights are uniformly 1/sum(l): accumulate
// raw O sums, scale once. Empty partials have l=0, O=0 (every strip's j=0
// block always runs kt=0, so denom > 0; ALL slots are written).
// ---------------------------------------------------------------------------
__global__ __launch_bounds__(256) void combine_kernel(
    const ushort* __restrict__ Opart, const float* __restrict__ Lp,
    ushort* __restrict__ Ab, int split)
{
  const int sid = blockIdx.x;
  const int bb = sid / 384, rem = sid % 384, h = rem >> 5, qt = rem & 31;
  const int t = threadIdx.x, row = t >> 2, cg = (t & 3) * 16;
  const float* lp = Lp + (size_t)sid * split * 64 + row;
  float denom = 0.0f;
  for (int i = 0; i < split; ++i) denom += lp[(size_t)i * 64];
  const float inv = 1.0f / denom;
  float os[16] = {};
  const ushort* p0 = Opart + (size_t)sid * split * 4096 + row * 64 + cg;
  for (int i = 0; i < split; ++i) {
#pragma unroll
    for (int g = 0; g < 2; ++g) {
      u4a a = *(const u4a*)(p0 + (size_t)i * 4096 + g * 8);
      os[g * 8 + 0] += blo(a.x); os[g * 8 + 1] += bhi(a.x);
      os[g * 8 + 2] += blo(a.y); os[g * 8 + 3] += bhi(a.y);
      os[g * 8 + 4] += blo(a.z); os[g * 8 + 5] += bhi(a.z);
      os[g * 8 + 6] += blo(a.w); os[g * 8 + 7] += bhi(a.w);
    }
  }
  ushort* dst = Ab + ((size_t)(bb * 2048 + qt * 64 + row)) * 768 + h * 64 + cg;
#pragma unroll
  for (int g = 0; g < 2; ++g) {
    u4a o;
    o.x = (uint32_t)f2b(os[g * 8 + 0] * inv) | ((uint32_t)f2b(os[g * 8 + 1] * inv) << 16);
    o.y = (uint32_t)f2b(os[g * 8 + 2] * inv) | ((uint32_t)f2b(os[g * 8 + 3] * inv) << 16);
    o.z = (uint32_t)f2b(os[g * 8 + 4] * inv) | ((uint32_t)f2b(os[g * 8 + 5] * inv) << 16);
    o.w = (uint32_t)f2b(os[g * 8 + 6] * inv) | ((uint32_t)f2b(os[g * 8 + 7] * inv) << 16);
    *(u4a*)(dst + g * 8) = o;
  }
}

// ---------------------------------------------------------------------------
extern "C" void kernel_launch(void* const* d_in, const int* in_sizes, int n_in,
                              void* d_out, int out_size, void* d_ws, size_t ws_size,
                              hipStream_t stream) {
  (void)in_sizes; (void)n_in; (void)out_size; (void)ws_size;
  const float* x  = (const float*)d_in[0];
  const float* wq = (const float*)d_in[1];
  const float* wk = (const float*)d_in[2];
  const float* wv = (const float*)d_in[3];
  const float* wo = (const float*)d_in[4];

  const size_t NT = (size_t)4096 * 768;   // tokens x d_model
  const size_t NW = (size_t)768 * 768;
  const size_t NV = (size_t)24 * 64 * VS; // padded Vt
  ushort* xb    = (ushort*)d_ws;          // reused as Abuf after QKV GEMM
  ushort* Qbuf  = xb + NT;
  ushort* Kbuf  = Qbuf + NT;
  ushort* Vt    = Kbuf + NT;              // (b, h, dv, s) stride VS
  ushort* wqb   = Vt + NV;
  ushort* wkb   = wqb + NW;
  ushort* wvb   = wkb + NW;
  ushort* wob   = wvb + NW;
  ushort* Opart = wob + NW;               // 3072 x 64 x 64 bf16
  float* Lp     = (float*)(Opart + (size_t)3072 * 4096);  // 3072 x 64
  ushort* Abuf  = xb;                     // lifetime-disjoint reuse

  // fp32 -> bf16 (x + all weights)
  convert_kernel<<<2688, 256, 0, stream>>>(x, wq, wk, wv, wo,
                                           xb, wqb, wkb, wvb, wob);
  // Q/K/V projections: r12 tile (128x64), flat 1152 grid + XCD swizzle
  gemm_qkv<<<1152, 256, 0, stream>>>(
      xb, wqb, wkb, wvb, Qbuf, Kbuf, Vt, 4096, 768, 768);
  // causal flash attention: r12 best (XCD swizzle, 4-way split, KVBLK=64)
  attn_kernel<<<1536, 256, 0, stream>>>(Qbuf, Kbuf, Vt, Opart, Lp);
  // merge partials -> Abuf
  combine_kernel<<<768, 256, 0, stream>>>(Opart, Lp, Abuf, 4);
  // output projection: r12 tile (64x64), flat 768 grid + XCD swizzle
  gemm_out<<<768, 256, 0, stream>>>(
      Abuf, wob, (float*)d_out, 4096, 768, 768);
}

// Round 17
// 156.012 us; speedup vs baseline: 1.0838x; 1.0293x over previous
//
#include <hip/hip_runtime.h>
#include <stdint.h>

typedef float f32x4 __attribute__((ext_vector_type(4)));
typedef __bf16 bf16x8 __attribute__((ext_vector_type(8)));
typedef uint32_t u32a  __attribute__((may_alias));
typedef uint2    u2a   __attribute__((may_alias));
typedef uint4    u4a   __attribute__((may_alias));

#define VS 2064   // Vt row stride in elements (2048 + 16: breaks 4KB L2 aliasing)

__device__ __forceinline__ ushort f2b(float f) {
  uint32_t u = __builtin_bit_cast(uint32_t, f);
  u += 0x7FFFu + ((u >> 16) & 1u);   // round-to-nearest-even
  return (ushort)(u >> 16);
}
__device__ __forceinline__ uint32_t b16(uint32_t u) {  // fp32 bits -> bf16 bits (RNE)
  u += 0x7FFFu + ((u >> 16) & 1u);
  return u >> 16;
}
__device__ __forceinline__ float blo(uint32_t a) {   // low bf16 -> f32
  return __builtin_bit_cast(float, a << 16);
}
__device__ __forceinline__ float bhi(uint32_t a) {   // high bf16 -> f32
  return __builtin_bit_cast(float, a & 0xFFFF0000u);
}

__device__ __forceinline__ bf16x8 ld_frag(const ushort* p) {
  u4a u = *(const u4a*)p;            // ds_read_b128 / global_load_dwordx4
  return __builtin_bit_cast(bf16x8, u);
}

// 8 fp32 -> 8 bf16 packed (two dwordx4 loads + RNE pack)
__device__ __forceinline__ u4a cvt8(const float* p) {
  u4a a = *(const u4a*)p, b = *(const u4a*)(p + 4), o;
  o.x = b16(a.x) | (b16(a.y) << 16);
  o.y = b16(a.z) | (b16(a.w) << 16);
  o.z = b16(b.x) | (b16(b.y) << 16);
  o.w = b16(b.z) | (b16(b.w) << 16);
  return o;
}

__device__ __forceinline__ void load_lds16(const void* g, void* l) {
  __builtin_amdgcn_global_load_lds(
      (const __attribute__((address_space(1))) uint32_t*)g,
      (__attribute__((address_space(3))) uint32_t*)l, 16, 0, 0);
}

// ---------------------------------------------------------------------------
// fp32 -> bf16 one-shot convert: x (3145728) then wq/wk/wv/wo (589824 each).
// ---------------------------------------------------------------------------
__global__ __launch_bounds__(256) void convert_kernel(
    const float* __restrict__ x,  const float* __restrict__ wq,
    const float* __restrict__ wk, const float* __restrict__ wv,
    const float* __restrict__ wo,
    ushort* __restrict__ xb,  ushort* __restrict__ wqb,
    ushort* __restrict__ wkb, ushort* __restrict__ wvb,
    ushort* __restrict__ wob)
{
  const size_t NX = 3145728, NW = 589824;
  size_t idx = ((size_t)blockIdx.x * 256 + threadIdx.x) * 8;
  const float* src; ushort* dst; size_t off;
  if      (idx < NX)          { src = x;  dst = xb;  off = idx; }
  else if (idx < NX + NW)     { src = wq; dst = wqb; off = idx - NX; }
  else if (idx < NX + 2 * NW) { src = wk; dst = wkb; off = idx - NX - NW; }
  else if (idx < NX + 3 * NW) { src = wv; dst = wvb; off = idx - NX - 2 * NW; }
  else                        { src = wo; dst = wob; off = idx - NX - 3 * NW; }
  *(u4a*)(dst + off) = cvt8(src + off);
}

// ---------------------------------------------------------------------------
// QKV: C[M,N]=A[M,K]*B[N,K]^T, bf16, fp32 acc. BM=128 BN=64 BK=64, 256 thr.
// grid (32, 12, 3): y-tile == one head. z: 0->Q (PRE-SCALED by log2(e)/8),
// 1->K row-major; 2->V written transposed to Vt[b][h][dv][s] (stride VS).
// (r14's 128x128 tile shrank the grid below one residency round on this
// skinny N=768 problem -> -13us; r15's XCD swizzle was within noise ->
// both reverted to this r12-proven form.)
// ---------------------------------------------------------------------------
__global__ __launch_bounds__(256) void gemm_qkv(
    const ushort* __restrict__ A,
    const ushort* __restrict__ B0, const ushort* __restrict__ B1,
    const ushort* __restrict__ B2,
    ushort* __restrict__ Qo, ushort* __restrict__ Ko, ushort* __restrict__ Vt,
    int M, int N, int K)
{
  const ushort* B = blockIdx.z == 0 ? B0 : (blockIdx.z == 1 ? B1 : B2);
  const int m0 = blockIdx.x * 128, n0 = blockIdx.y * 64;
  __shared__ ushort As[128 * 64];   // 16KB, linear chunk order (8 chunks/row)
  __shared__ ushort Bs[64 * 64];    // 8KB
  const int tid = threadIdx.x, wave = tid >> 6, lane = tid & 63;
  const int quad = lane >> 4, l16 = lane & 15;
  const int mw = (wave & 1) * 64, nw = (wave >> 1) * 32;
  f32x4 acc[4][2] = {};

  for (int k0 = 0; k0 < K; k0 += 64) {
    // A: 1024 chunks of 16B (4/thread); chunk c -> row c>>3, col (c&7)*8
#pragma unroll
    for (int i = 0; i < 4; ++i) {
      int c = i * 256 + tid;
      load_lds16(A + (size_t)(m0 + (c >> 3)) * K + k0 + (c & 7) * 8,
                 As + (size_t)(i * 256 + wave * 64) * 8);
    }
    // B: 512 chunks (2/thread)
#pragma unroll
    for (int i = 0; i < 2; ++i) {
      int c = i * 256 + tid;
      load_lds16(B + (size_t)(n0 + (c >> 3)) * K + k0 + (c & 7) * 8,
                 Bs + (size_t)(i * 256 + wave * 64) * 8);
    }
    __syncthreads();
#pragma unroll
    for (int ks = 0; ks < 2; ++ks) {
      bf16x8 af[4], bfr[2];
#pragma unroll
      for (int i = 0; i < 4; ++i)
        af[i]  = ld_frag(As + (mw + i * 16 + l16) * 64 + ks * 32 + quad * 8);
#pragma unroll
      for (int j = 0; j < 2; ++j)
        bfr[j] = ld_frag(Bs + (nw + j * 16 + l16) * 64 + ks * 32 + quad * 8);
#pragma unroll
      for (int i = 0; i < 4; ++i)
#pragma unroll
        for (int j = 0; j < 2; ++j)
          acc[i][j] = __builtin_amdgcn_mfma_f32_16x16x32_bf16(af[i], bfr[j], acc[i][j], 0, 0, 0);
    }
    __syncthreads();
  }
  // C/D layout: col=lane&15 (N), row=quad*4+reg (M)
  if (blockIdx.z < 2) {
    ushort* C = blockIdx.z == 0 ? Qo : Ko;
    // fold 1/sqrt(dk) AND log2(e) into Q so attention uses exp2 directly
    const float sc = blockIdx.z == 0 ? 0.18033688f : 1.0f;
#pragma unroll
    for (int i = 0; i < 4; ++i)
#pragma unroll
      for (int j = 0; j < 2; ++j)
#pragma unroll
        for (int r = 0; r < 4; ++r) {
          int row = m0 + mw + i * 16 + quad * 4 + r;
          int col = n0 + nw + j * 16 + l16;
          C[(size_t)row * N + col] = f2b(acc[i][j][r] * sc);
        }
  } else {
    // Vt[b][h][dv][s] (stride VS): h == blockIdx.y, dv = col&63
#pragma unroll
    for (int i = 0; i < 4; ++i)
#pragma unroll
      for (int j = 0; j < 2; ++j) {
        int col = n0 + nw + j * 16 + l16;
        int h = col >> 6, dv = col & 63;
        int t = m0 + mw + i * 16 + quad * 4;
        int b = t >> 11, s = t & 2047;
        u2a pw;
        pw.x = (uint32_t)f2b(acc[i][j][0]) | ((uint32_t)f2b(acc[i][j][1]) << 16);
        pw.y = (uint32_t)f2b(acc[i][j][2]) | ((uint32_t)f2b(acc[i][j][3]) << 16);
        *(u2a*)(Vt + (((size_t)b * 12 + h) * 64 + dv) * VS + s) = pw;
      }
  }
}

// ---------------------------------------------------------------------------
// Output projection: C[M,N](fp32) = A[M,K](bf16)*B[N,K]^T(bf16).
// BM=BN=64, BK=64, 256 thr, grid (64,12) = 768 blocks (3/CU, one round).
// ---------------------------------------------------------------------------
__global__ __launch_bounds__(256) void gemm_out(
    const ushort* __restrict__ A, const ushort* __restrict__ B,
    float* __restrict__ C, int M, int N, int K)
{
  const int m0 = blockIdx.x * 64, n0 = blockIdx.y * 64;
  __shared__ ushort As[64 * 64];
  __shared__ ushort Bs[64 * 64];
  const int tid = threadIdx.x, wave = tid >> 6, lane = tid & 63;
  const int quad = lane >> 4, l16 = lane & 15;
  const int mw = (wave & 1) * 32, nw = (wave >> 1) * 32;
  f32x4 acc[2][2] = {};

  for (int k0 = 0; k0 < K; k0 += 64) {
#pragma unroll
    for (int i = 0; i < 2; ++i) {
      int c = i * 256 + tid;
      load_lds16(A + (size_t)(m0 + (c >> 3)) * K + k0 + (c & 7) * 8,
                 As + (size_t)(i * 256 + wave * 64) * 8);
      load_lds16(B + (size_t)(n0 + (c >> 3)) * K + k0 + (c & 7) * 8,
                 Bs + (size_t)(i * 256 + wave * 64) * 8);
    }
    __syncthreads();
#pragma unroll
    for (int ks = 0; ks < 2; ++ks) {
      bf16x8 af[2], bfr[2];
#pragma unroll
      for (int i = 0; i < 2; ++i)
        af[i]  = ld_frag(As + (mw + i * 16 + l16) * 64 + ks * 32 + quad * 8);
#pragma unroll
      for (int j = 0; j < 2; ++j)
        bfr[j] = ld_frag(Bs + (nw + j * 16 + l16) * 64 + ks * 32 + quad * 8);
#pragma unroll
      for (int i = 0; i < 2; ++i)
#pragma unroll
        for (int j = 0; j < 2; ++j)
          acc[i][j] = __builtin_amdgcn_mfma_f32_16x16x32_bf16(af[i], bfr[j], acc[i][j], 0, 0, 0);
    }
    __syncthreads();
  }
#pragma unroll
  for (int i = 0; i < 2; ++i)
#pragma unroll
    for (int j = 0; j < 2; ++j)
#pragma unroll
      for (int r = 0; r < 4; ++r) {
        int row = m0 + mw + i * 16 + quad * 4 + r;
        int col = n0 + nw + j * 16 + l16;
        C[(size_t)row * N + col] = acc[i][j][r];
      }
}

// ---------------------------------------------------------------------------
// Causal flash attention (ROUND-12 BEST): TILE-SHARED strips, 4-way K-split,
// KVBLK=64, pad-72 LDS, XCD-AWARE SWIZZLE. Flat grid 1536;
// nf=(fid&7)*192+(fid>>3) (bijective, 1536=8*192) gives each XCD 3
// contiguous (bb,h) groups of 64 blocks sharing the same 512 KB of K/V ->
// per-XCD L2 working set ~1.5 MB (vs 12 MB round-robin) -> staging hits L2.
//
// FIXED-BASE softmax (r6): scores in log2 units (Q pre-scaled by log2e/8),
// |s| <~ 10 << 127 -> P = 2^s directly, base m=0; no max, no rescale, no
// cross-lane ops in the loop. l row-sum via MFMA-ones (r7): l[q] lands in
// acc_l[r] (q = wave*16+quad*4+r, uniform over l16). P-pack via v_perm (r7).
// P never touches LDS: PV uses the permuted contraction index
//   kk = g*32 + (e>>2)*16 + quad*4 + (e&3);
// V staged into Vs in the same permuted order (read stays ds_read_b128).
// VGPR ~96 (<=128 mandatory: r2's 160 -> 2 blk/CU disaster; r1's
// launch_bounds coercion -> 660MB spills).
// Refuted levers kept OUT: dbuf (r9 iso-grid), strip fusion (r10),
// KVBLK=128 (r13), 8-way split (r5), 2-way split (r8).
// Emits unnormalized partials + l per strip (m ≡ 0 for all partials).
// ---------------------------------------------------------------------------
__global__ __launch_bounds__(256) void attn_kernel(
    const ushort* __restrict__ Qb, const ushort* __restrict__ Kb,
    const ushort* __restrict__ Vt, ushort* __restrict__ Opart,
    float* __restrict__ Lp)
{
  const int S = 2048, DM = 768;
  const int fid = blockIdx.x;
  const int nf  = (fid & 7) * 192 + (fid >> 3);
  const int grp = nf >> 6;            // 0..23  == bb*12 + h
  const int wit = nf & 63;            // pair*4 + j
  const int bb = grp / 12, h = grp % 12;
  const int pair = wit >> 2, j = wit & 3;

  const ushort* Qp  = Qb + (size_t)bb * S * DM + h * 64;
  const ushort* Kp  = Kb + (size_t)bb * S * DM + h * 64;
  const ushort* Vth = Vt + ((size_t)bb * 12 + h) * 64 * VS;   // [dv][s]

  __shared__ ushort Ks[64 * 72];     // [kk][dk], pad 64->72 (9.2 KB)
  __shared__ ushort Vs[64 * 72];     // [dv][kk-permuted], pad 64->72 (9.2 KB)

  const int tid = threadIdx.x, wave = tid >> 6, lane = tid & 63;
  const int quad = lane >> 4, l16 = lane & 15;
  const float NEG_BIG = -1.0e30f;

  const int qtA = pair, qtB = 31 - pair;       // 64-row q-tiles
  const int qgA = qtA * 64 + wave * 16 + l16;
  const int qgB = qtB * 64 + wave * 16 + l16;

  // Q fragments for both strips (B operand of S^T = K*Q^T)
  bf16x8 bqA0 = ld_frag(Qp + (size_t)qgA * DM + quad * 8);
  bf16x8 bqA1 = ld_frag(Qp + (size_t)qgA * DM + 32 + quad * 8);
  bf16x8 bqB0 = ld_frag(Qp + (size_t)qgB * DM + quad * 8);
  bf16x8 bqB1 = ld_frag(Qp + (size_t)qgB * DM + 32 + quad * 8);

  // ones B-operand for the l row-sum MFMA (bf16 1.0 = 0x3F80)
  u4a one4; one4.x = one4.y = one4.z = one4.w = 0x3F803F80u;
  const bf16x8 ones = __builtin_bit_cast(bf16x8, one4);

  f32x4 accA[4] = {}, accB[4] = {};
  f32x4 alA = {}, alB = {};          // l accumulators (q = wave*16+quad*4+r)

  for (int kt = j; kt <= qtB; kt += 4) {
    const int kk0 = kt * 64;
    // stage K tile: 512 chunks of 16B (2/thread); chunk c -> row c>>3, col (c&7)*8
#pragma unroll
    for (int i = 0; i < 2; ++i) {
      int c = i * 256 + tid;
      int r = c >> 3, col = (c & 7) * 8;
      *(u4a*)(Ks + r * 72 + col) = *(const u4a*)(Kp + (size_t)(kk0 + r) * DM + col);
    }
    // stage V tile from Vt with kk-permuted placement:
    // chunk c -> dv c>>3, global kk run (c&7)*8..+7 lands at
    // pos = (kc8>>2)*32 + (kc8&1)*16 + ((kc8>>1)&1)*4  (first 4) and pos+8.
#pragma unroll
    for (int i = 0; i < 2; ++i) {
      int c = i * 256 + tid;
      int dv = c >> 3, kc8 = c & 7;
      u4a g = *(const u4a*)(Vth + (size_t)dv * VS + kk0 + kc8 * 8);
      int pos = ((kc8 >> 2) * 32) + ((kc8 & 1) * 16) + (((kc8 >> 1) & 1) * 4);
      u2a lo, hi;
      lo.x = g.x; lo.y = g.y; hi.x = g.z; hi.y = g.w;
      *(u2a*)(Vs + dv * 72 + pos)     = lo;
      *(u2a*)(Vs + dv * 72 + pos + 8) = hi;
    }
    __syncthreads();

    // ---- compute one strip from the staged tile (fixed-base softmax) ----
    auto strip = [&](const bf16x8& bq0, const bf16x8& bq1, f32x4* acc_o,
                     f32x4& acc_l, int qg, bool domask) {
      // S^T strip: this wave's 16 q cols x 64 kk rows = 4 tiles
      f32x4 sacc[4] = {};
#pragma unroll
      for (int tt = 0; tt < 4; ++tt) {
        bf16x8 ak0 = ld_frag(Ks + (tt * 16 + l16) * 72 + quad * 8);
        bf16x8 ak1 = ld_frag(Ks + (tt * 16 + l16) * 72 + 32 + quad * 8);
        sacc[tt] = __builtin_amdgcn_mfma_f32_16x16x32_bf16(ak0, bq0, sacc[tt], 0, 0, 0);
        sacc[tt] = __builtin_amdgcn_mfma_f32_16x16x32_bf16(ak1, bq1, sacc[tt], 0, 0, 0);
      }
      // causal mask (diagonal tile only; block-uniform predicate)
      if (domask) {
#pragma unroll
        for (int tt = 0; tt < 4; ++tt)
#pragma unroll
          for (int r = 0; r < 4; ++r) {
            int kkg = kk0 + tt * 16 + quad * 4 + r;
            if (kkg > qg) sacc[tt][r] = NEG_BIG;
          }
      }
      // fused P = 2^s + perm-pack + PV per 32-wide k-group; l via MFMA-ones.
#pragma unroll
      for (int g = 0; g < 2; ++g) {
        u4a pu;
        {
          int tt = g * 2;
          uint32_t u0 = __builtin_bit_cast(uint32_t, exp2f(sacc[tt][0]));
          uint32_t u1 = __builtin_bit_cast(uint32_t, exp2f(sacc[tt][1]));
          uint32_t u2 = __builtin_bit_cast(uint32_t, exp2f(sacc[tt][2]));
          uint32_t u3 = __builtin_bit_cast(uint32_t, exp2f(sacc[tt][3]));
          pu.x = __builtin_amdgcn_perm(u1, u0, 0x07060302u);  // {u1.hi,u0.hi}
          pu.y = __builtin_amdgcn_perm(u3, u2, 0x07060302u);
          u0 = __builtin_bit_cast(uint32_t, exp2f(sacc[tt + 1][0]));
          u1 = __builtin_bit_cast(uint32_t, exp2f(sacc[tt + 1][1]));
          u2 = __builtin_bit_cast(uint32_t, exp2f(sacc[tt + 1][2]));
          u3 = __builtin_bit_cast(uint32_t, exp2f(sacc[tt + 1][3]));
          pu.z = __builtin_amdgcn_perm(u1, u0, 0x07060302u);
          pu.w = __builtin_amdgcn_perm(u3, u2, 0x07060302u);
        }
        bf16x8 ap = __builtin_bit_cast(bf16x8, pu);
        acc_l = __builtin_amdgcn_mfma_f32_16x16x32_bf16(ap, ones, acc_l, 0, 0, 0);
#pragma unroll
        for (int ct = 0; ct < 4; ++ct) {
          bf16x8 bv = ld_frag(Vs + (size_t)(ct * 16 + l16) * 72 + g * 32 + quad * 8);
          acc_o[ct] = __builtin_amdgcn_mfma_f32_16x16x32_bf16(ap, bv, acc_o[ct], 0, 0, 0);
        }
      }
    };

    strip(bqB0, bqB1, accB, alB, qgB, kt == qtB);     // always active
    if (kt <= qtA)
      strip(bqA0, bqA1, accA, alA, qgA, kt == qtA);   // block-uniform branch
    __syncthreads();   // protect Ks/Vs before next restage
  }

  // epilogue: store partials; l for q=wave*16+quad*4+r is acc_l[r],
  // identical across l16 lanes -> store from l16==0.
  const int base = ((bb * 12 + h) << 5);
  const int r0 = wave * 16 + quad * 4;
  {
    const int slot = (base + qtB) * 4 + j;
    ushort* Os = Opart + (size_t)slot * 4096;
#pragma unroll
    for (int ct = 0; ct < 4; ++ct) {
      int col = ct * 16 + l16;
      Os[(r0 + 0) * 64 + col] = f2b(accB[ct][0]);
      Os[(r0 + 1) * 64 + col] = f2b(accB[ct][1]);
      Os[(r0 + 2) * 64 + col] = f2b(accB[ct][2]);
      Os[(r0 + 3) * 64 + col] = f2b(accB[ct][3]);
    }
    if (l16 == 0) {
#pragma unroll
      for (int r = 0; r < 4; ++r)
        Lp[(size_t)slot * 64 + r0 + r] = alB[r];
    }
  }
  {
    const int slot = (base + qtA) * 4 + j;
    ushort* Os = Opart + (size_t)slot * 4096;
#pragma unroll
    for (int ct = 0; ct < 4; ++ct) {
      int col = ct * 16 + l16;
      Os[(r0 + 0) * 64 + col] = f2b(accA[ct][0]);
      Os[(r0 + 1) * 64 + col] = f2b(accA[ct][1]);
      Os[(r0 + 2) * 64 + col] = f2b(accA[ct][2]);
      Os[(r0 + 3) * 64 + col] = f2b(accA[ct][3]);
    }
    if (l16 == 0) {
#pragma unroll
      for (int r = 0; r < 4; ++r)
        Lp[(size_t)slot * 64 + r0 + r] = alA[r];
    }
  }
}

// ---------------------------------------------------------------------------
// Combine the four K-parity partials per strip -> Abuf (b, s, h*64) bf16.
// grid 768 (one block per strip), 256 threads, 16 elems/thread.
// All partials share base m=0 -> weights are uniformly 1/sum(l): accumulate
// raw O sums, scale once. Empty partials have l=0, O=0 (every strip's j=0
// block always runs kt=0, so denom > 0; ALL slots are written).
// ---------------------------------------------------------------------------
__global__ __launch_bounds__(256) void combine_kernel(
    const ushort* __restrict__ Opart, const float* __restrict__ Lp,
    ushort* __restrict__ Ab, int split)
{
  const int sid = blockIdx.x;
  const int bb = sid / 384, rem = sid % 384, h = rem >> 5, qt = rem & 31;
  const int t = threadIdx.x, row = t >> 2, cg = (t & 3) * 16;
  const float* lp = Lp + (size_t)sid * split * 64 + row;
  float denom = 0.0f;
  for (int i = 0; i < split; ++i) denom += lp[(size_t)i * 64];
  const float inv = 1.0f / denom;
  float os[16] = {};
  const ushort* p0 = Opart + (size_t)sid * split * 4096 + row * 64 + cg;
  for (int i = 0; i < split; ++i) {
#pragma unroll
    for (int g = 0; g < 2; ++g) {
      u4a a = *(const u4a*)(p0 + (size_t)i * 4096 + g * 8);
      os[g * 8 + 0] += blo(a.x); os[g * 8 + 1] += bhi(a.x);
      os[g * 8 + 2] += blo(a.y); os[g * 8 + 3] += bhi(a.y);
      os[g * 8 + 4] += blo(a.z); os[g * 8 + 5] += bhi(a.z);
      os[g * 8 + 6] += blo(a.w); os[g * 8 + 7] += bhi(a.w);
    }
  }
  ushort* dst = Ab + ((size_t)(bb * 2048 + qt * 64 + row)) * 768 + h * 64 + cg;
#pragma unroll
  for (int g = 0; g < 2; ++g) {
    u4a o;
    o.x = (uint32_t)f2b(os[g * 8 + 0] * inv) | ((uint32_t)f2b(os[g * 8 + 1] * inv) << 16);
    o.y = (uint32_t)f2b(os[g * 8 + 2] * inv) | ((uint32_t)f2b(os[g * 8 + 3] * inv) << 16);
    o.z = (uint32_t)f2b(os[g * 8 + 4] * inv) | ((uint32_t)f2b(os[g * 8 + 5] * inv) << 16);
    o.w = (uint32_t)f2b(os[g * 8 + 6] * inv) | ((uint32_t)f2b(os[g * 8 + 7] * inv) << 16);
    *(u4a*)(dst + g * 8) = o;
  }
}

// ---------------------------------------------------------------------------
extern "C" void kernel_launch(void* const* d_in, const int* in_sizes, int n_in,
                              void* d_out, int out_size, void* d_ws, size_t ws_size,
                              hipStream_t stream) {
  (void)in_sizes; (void)n_in; (void)out_size; (void)ws_size;
  const float* x  = (const float*)d_in[0];
  const float* wq = (const float*)d_in[1];
  const float* wk = (const float*)d_in[2];
  const float* wv = (const float*)d_in[3];
  const float* wo = (const float*)d_in[4];

  const size_t NT = (size_t)4096 * 768;   // tokens x d_model
  const size_t NW = (size_t)768 * 768;
  const size_t NV = (size_t)24 * 64 * VS; // padded Vt
  ushort* xb    = (ushort*)d_ws;          // reused as Abuf after QKV GEMM
  ushort* Qbuf  = xb + NT;
  ushort* Kbuf  = Qbuf + NT;
  ushort* Vt    = Kbuf + NT;              // (b, h, dv, s) stride VS
  ushort* wqb   = Vt + NV;
  ushort* wkb   = wqb + NW;
  ushort* wvb   = wkb + NW;
  ushort* wob   = wvb + NW;
  ushort* Opart = wob + NW;               // 3072 x 64 x 64 bf16
  float* Lp     = (float*)(Opart + (size_t)3072 * 4096);  // 3072 x 64
  ushort* Abuf  = xb;                     // lifetime-disjoint reuse

  // fp32 -> bf16 (x + all weights)
  convert_kernel<<<2688, 256, 0, stream>>>(x, wq, wk, wv, wo,
                                           xb, wqb, wkb, wvb, wob);
  // Q/K/V projections (Q pre-scaled by log2e/8; V lands transposed in Vt)
  gemm_qkv<<<dim3(32, 12, 3), 256, 0, stream>>>(
      xb, wqb, wkb, wvb, Qbuf, Kbuf, Vt, 4096, 768, 768);
  // causal flash attention: r12 best (XCD swizzle, 4-way split, KVBLK=64)
  attn_kernel<<<1536, 256, 0, stream>>>(Qbuf, Kbuf, Vt, Opart, Lp);
  // merge partials -> Abuf
  combine_kernel<<<768, 256, 0, stream>>>(Opart, Lp, Abuf, 4);
  // output projection (fp32 out)
  gemm_out<<<dim3(64, 12), 256, 0, stream>>>(
      Abuf, wob, (float*)d_out, 4096, 768, 768);
}